// Round 4
// baseline (243.037 us; speedup 1.0000x reference)
//
#include <hip/hip_runtime.h>
#include <hip/hip_bf16.h>
#include <math.h>

#define B_   4
#define S_   2048
#define DIN  1024
#define DATT 1024
#define DHID 1024

typedef short bf16x8 __attribute__((ext_vector_type(8)));
typedef float f32x4  __attribute__((ext_vector_type(4)));

__device__ inline unsigned short f2bf(float f) {
    unsigned u = __float_as_uint(f);
    u += 0x7fffu + ((u >> 16) & 1u);
    return (unsigned short)(u >> 16);
}
__device__ inline float bf2f(unsigned u16) {
    return __uint_as_float(u16 << 16);
}
__device__ inline void gld16(const void* g, void* l) {
    __builtin_amdgcn_global_load_lds(
        (const __attribute__((address_space(1))) unsigned int*)g,
        (__attribute__((address_space(3))) unsigned int*)l, 16, 0, 0);
}

// ---------------- prep: X fp32 -> bf16 ----------------
__global__ __launch_bounds__(256)
void xcvt_k(const float* __restrict__ x, unsigned short* __restrict__ xb)
{
    int i = blockIdx.x * 256 + threadIdx.x;
    const float4* p = (const float4*)x + (size_t)i * 2;
    float4 v0 = p[0], v1 = p[1];
    uint4 o;
    o.x = (unsigned)f2bf(v0.x) | ((unsigned)f2bf(v0.y) << 16);
    o.y = (unsigned)f2bf(v0.z) | ((unsigned)f2bf(v0.w) << 16);
    o.z = (unsigned)f2bf(v1.x) | ((unsigned)f2bf(v1.y) << 16);
    o.w = (unsigned)f2bf(v1.z) | ((unsigned)f2bf(v1.w) << 16);
    ((uint4*)xb)[i] = o;
}

// ---------------- prep: W [K][N] fp32 -> Wt [N][K] bf16 ----------------
__global__ __launch_bounds__(256)
void wcvt_k(const float* __restrict__ Wq, const float* __restrict__ Wk,
            const float* __restrict__ Wv, unsigned short* __restrict__ Wt)
{
    int w = blockIdx.y;
    const float* W = (w == 0) ? Wq : ((w == 1) ? Wk : Wv);
    unsigned short* D = Wt + (size_t)w * DIN * DATT;
    int t = blockIdx.x * 256 + threadIdx.x;
    int n  = t >> 6;
    int kc = (t & 63) * 16;
    unsigned short r[16];
#pragma unroll
    for (int i = 0; i < 16; ++i) r[i] = f2bf(W[(size_t)(kc + i) * DATT + n]);
    uint4 o0, o1;
    o0.x = (unsigned)r[0] | ((unsigned)r[1] << 16);  o0.y = (unsigned)r[2] | ((unsigned)r[3] << 16);
    o0.z = (unsigned)r[4] | ((unsigned)r[5] << 16);  o0.w = (unsigned)r[6] | ((unsigned)r[7] << 16);
    o1.x = (unsigned)r[8] | ((unsigned)r[9] << 16);  o1.y = (unsigned)r[10] | ((unsigned)r[11] << 16);
    o1.z = (unsigned)r[12] | ((unsigned)r[13] << 16); o1.w = (unsigned)r[14] | ((unsigned)r[15] << 16);
    *(uint4*)(D + (size_t)n * DIN + kc)     = o0;
    *(uint4*)(D + (size_t)n * DIN + kc + 8) = o1;
}

// ======== 256x256 8-wave phase-interleaved GEMM (BK=64, counted vmcnt) ========
// A bf16 row-major [M][K]; B bf16 row-major [N][K].
// LDS per buffer (64KB): A at 0: row-permuted [256][64], byte = Rl*128 + (slot^(Rl&7))*16,
//   lds row Rl <-> global row gr: bit6<->bit7 swap (so phase mh reads Rl in [mh*128, mh*128+128)).
// B at 32768: kk-major [2][256][32], byte = kk*16384 + Rb*64 + ((lg^((Rb>>1)&3))*16).
// Stage rounds (1 gld/thread, 8KB): A r: lds rows 64r..; B r: kk=r>>1, rows (r&1)*128..
// Phase p=(mh=p&1? see order) consumes; stage schedule ph0:{A0,B0} ph1:{A1,B1} ph2:{A2,A3} ph3:{B2,B3}.
// EPI: 6 = fused QKV (Q/K bf16+bias; V gelu+bias transposed to Cp2)
//      4 = e = exp(val*scale) masked->0, bf16
//      5 = fp32 out * invs[row]
template<int EPI>
__global__ __launch_bounds__(512, 2)
void gemm256_k(const unsigned short* __restrict__ Ap, const unsigned short* __restrict__ Bp,
               const float* __restrict__ b0, const float* __restrict__ b1,
               const float* __restrict__ b2, const int* __restrict__ maskp,
               void* __restrict__ Cp, void* __restrict__ Cp2,
               int K, int lda, int ldb, int ldc,
               long aStride, long bStride, long cStride, long mStride, float scale)
{
    __shared__ __align__(16) char ldsb[131072];   // 2 x 64KB buffers

    const int tid  = threadIdx.x;
    const int z    = blockIdx.z;
    const int row0 = blockIdx.y * 256;
    const int col0 = blockIdx.x * 256;
    const int wid  = tid >> 6, lane = tid & 63;
    const int lr = lane & 15, lg = lane >> 4;
    const int wm = wid >> 2, wn = wid & 3;          // 2 x 4 wave grid
    const int tw = (tid & 448) * 16;                 // wave-uniform LDS stage base part

    const unsigned short* Ab = Ap + (size_t)aStride * z;
    const unsigned short* Bb = Bp + (size_t)bStride * z;

    const int swzA = lr & 7;                 // A slot xor key
    const int swzB = lg ^ ((lr >> 1) & 3);   // B slot (constant per lane)

    f32x4 acc[8][4] = {};
    const int nt = K >> 6;

#define STAGE_A(buf, k0n, r) {                                                  \
    int gr = (((r) & 1) << 7) + (((r) >> 1) << 6) + (tid >> 3);                 \
    int jj = (tid & 7) ^ (gr & 7);                                              \
    gld16(Ab + (size_t)(row0 + gr) * lda + (k0n) + jj * 8,                      \
          ldsb + (size_t)(buf) * 65536 + (r) * 8192 + tw); }

#define STAGE_B(buf, k0n, r) {                                                  \
    int rw = (((r) & 1) << 7) + (tid >> 2);                                     \
    int jj = (tid & 3) ^ ((rw >> 1) & 3);                                       \
    gld16(Bb + (size_t)(col0 + rw) * ldb + (k0n) + ((r) >> 1) * 32 + jj * 8,    \
          ldsb + (size_t)(buf) * 65536 + 32768 + ((r) >> 1) * 16384             \
               + (((r) & 1) << 13) + tw); }

#define PHASE(mh, kk, DOSTAGE) {                                                \
    const char* lb = ldsb + (size_t)cb * 65536;                                 \
    bf16x8 av[4], bv[4];                                                        \
    _Pragma("unroll")                                                           \
    for (int m = 0; m < 4; ++m) {                                               \
        int Rl = (mh) * 128 + wm * 64 + m * 16 + lr;                            \
        av[m] = *(const bf16x8*)(lb + Rl * 128 + ((((kk) * 4 + lg) ^ swzA) * 16)); \
    }                                                                           \
    _Pragma("unroll")                                                           \
    for (int n = 0; n < 4; ++n) {                                               \
        int Rb = wn * 64 + n * 16 + lr;                                         \
        bv[n] = *(const bf16x8*)(lb + 32768 + (kk) * 16384 + Rb * 64 + swzB * 16); \
    }                                                                           \
    DOSTAGE;                                                                    \
    asm volatile("s_waitcnt lgkmcnt(0)" ::: "memory");                          \
    __builtin_amdgcn_sched_barrier(0);                                          \
    __builtin_amdgcn_s_setprio(1);                                              \
    _Pragma("unroll")                                                           \
    for (int m = 0; m < 4; ++m)                                                 \
        _Pragma("unroll")                                                       \
        for (int n = 0; n < 4; ++n)                                             \
            acc[(mh) * 4 + m][n] = __builtin_amdgcn_mfma_f32_16x16x32_bf16(     \
                av[m], bv[n], acc[(mh) * 4 + m][n], 0, 0, 0);                   \
    __builtin_amdgcn_s_setprio(0); }

    // prologue: stage tile 0 in ledger order
    STAGE_A(0, 0, 0); STAGE_B(0, 0, 0);
    STAGE_A(0, 0, 1); STAGE_B(0, 0, 1);
    STAGE_A(0, 0, 2); STAGE_A(0, 0, 3);
    STAGE_B(0, 0, 2); STAGE_B(0, 0, 3);

    int cb = 0;
    for (int t = 0; t < nt; ++t) {
        const bool pf = (t + 1) < nt;
        const int k0n = (t + 1) << 6;
        const int nb = cb ^ 1;
        asm volatile("s_waitcnt vmcnt(4)\ns_barrier" ::: "memory");
        PHASE(0, 0, if (pf) { STAGE_A(nb, k0n, 0); STAGE_B(nb, k0n, 0); })
        if (pf) asm volatile("s_waitcnt vmcnt(4)\ns_barrier" ::: "memory");
        else    asm volatile("s_waitcnt vmcnt(2)\ns_barrier" ::: "memory");
        PHASE(1, 0, if (pf) { STAGE_A(nb, k0n, 1); STAGE_B(nb, k0n, 1); })
        if (pf) asm volatile("s_waitcnt vmcnt(4)\ns_barrier" ::: "memory");
        else    asm volatile("s_waitcnt vmcnt(0)\ns_barrier" ::: "memory");
        PHASE(0, 1, if (pf) { STAGE_A(nb, k0n, 2); STAGE_A(nb, k0n, 3); })
        PHASE(1, 1, if (pf) { STAGE_B(nb, k0n, 2); STAGE_B(nb, k0n, 3); })
        cb = nb;
    }
#undef PHASE
#undef STAGE_A
#undef STAGE_B

    // ---- epilogue ----  row = row0 + wm*128 + mi*16 + lg*4 + v ; col = col0 + wn*64 + ni*16 + lr
    if (EPI == 6) {
        int w = col0 >> 10;
        int cb0 = (col0 & 1023) + wn * 64;
        if (w < 2) {
            unsigned short* C = (unsigned short*)Cp + (size_t)w * ((size_t)B_ * S_ * DATT);
            const float* bias = w ? b1 : b0;
#pragma unroll
            for (int ni = 0; ni < 4; ++ni) {
                int col = cb0 + ni * 16 + lr;
                float bb = bias[col];
#pragma unroll
                for (int mi = 0; mi < 8; ++mi) {
                    int rowb = row0 + wm * 128 + mi * 16 + lg * 4;
#pragma unroll
                    for (int v = 0; v < 4; ++v)
                        C[(size_t)(rowb + v) * DATT + col] = f2bf(acc[mi][ni][v] + bb);
                }
            }
        } else {
            unsigned short* C = (unsigned short*)Cp2;
            int zz = row0 >> 11;
            int sb = (row0 & 2047) + wm * 128;
#pragma unroll
            for (int ni = 0; ni < 4; ++ni) {
                int col = cb0 + ni * 16 + lr;
                float bb = b2[col];
#pragma unroll
                for (int mi = 0; mi < 8; ++mi) {
                    unsigned short r[4];
#pragma unroll
                    for (int v = 0; v < 4; ++v) {
                        float xv = acc[mi][ni][v] + bb;
                        xv = 0.5f * xv * (1.0f + erff(xv * 0.70710678118654752f));
                        r[v] = f2bf(xv);
                    }
                    uint2 o;
                    o.x = (unsigned)r[0] | ((unsigned)r[1] << 16);
                    o.y = (unsigned)r[2] | ((unsigned)r[3] << 16);
                    *(uint2*)(C + ((size_t)zz * DHID + col) * S_ + sb + mi * 16 + lg * 4) = o;
                }
            }
        }
    } else if (EPI == 4) {
        unsigned short* C = (unsigned short*)Cp + (size_t)cStride * z;
        const int* mp = maskp + (size_t)mStride * z;
#pragma unroll
        for (int mi = 0; mi < 8; ++mi) {
            int rowb = row0 + wm * 128 + mi * 16 + lg * 4;
#pragma unroll
            for (int ni = 0; ni < 4; ++ni) {
                int col = col0 + wn * 64 + ni * 16 + lr;
#pragma unroll
                for (int v = 0; v < 4; ++v) {
                    float sv = acc[mi][ni][v] * scale;
                    int mk = mp[(size_t)(rowb + v) * ldc + col];
                    float ev = mk ? 0.0f : __expf(sv);
                    C[(size_t)(rowb + v) * ldc + col] = f2bf(ev);
                }
            }
        }
    } else {  // EPI == 5
        float* C = (float*)Cp + (size_t)cStride * z;
        const float* invs = b0 + (size_t)z * S_;
#pragma unroll
        for (int mi = 0; mi < 8; ++mi) {
            int rowb = row0 + wm * 128 + mi * 16 + lg * 4;
#pragma unroll
            for (int ni = 0; ni < 4; ++ni) {
                int col = col0 + wn * 64 + ni * 16 + lr;
#pragma unroll
                for (int v = 0; v < 4; ++v)
                    C[(size_t)(rowb + v) * ldc + col] = acc[mi][ni][v] * invs[rowb + v];
            }
        }
    }
}

// ---------------- rowsum / normalize over e (bf16 rows of 2048) ----------------
template<bool WRITEATTN>
__global__ __launch_bounds__(256)
void rownorm_k(const unsigned short* __restrict__ e, float* __restrict__ attn,
               float* __restrict__ invs)
{
    const int row = blockIdx.x;
    const int tid = threadIdx.x;
    uint4 u = ((const uint4*)(e + (size_t)row * S_))[tid];
    float f[8];
    f[0] = bf2f(u.x & 0xffffu); f[1] = bf2f(u.x >> 16);
    f[2] = bf2f(u.y & 0xffffu); f[3] = bf2f(u.y >> 16);
    f[4] = bf2f(u.z & 0xffffu); f[5] = bf2f(u.z >> 16);
    f[6] = bf2f(u.w & 0xffffu); f[7] = bf2f(u.w >> 16);
    float s = ((f[0] + f[1]) + (f[2] + f[3])) + ((f[4] + f[5]) + (f[6] + f[7]));
#pragma unroll
    for (int o = 32; o; o >>= 1) s += __shfl_xor(s, o);
    __shared__ float red[4];
    if ((tid & 63) == 0) red[tid >> 6] = s;
    __syncthreads();
    s = (red[0] + red[1]) + (red[2] + red[3]);
    float inv = 1.0f / s;
    if (WRITEATTN) {
        float* p = attn + (size_t)row * S_;
        ((float4*)p)[tid * 2]     = make_float4(f[0] * inv, f[1] * inv, f[2] * inv, f[3] * inv);
        ((float4*)p)[tid * 2 + 1] = make_float4(f[4] * inv, f[5] * inv, f[6] * inv, f[7] * inv);
    } else {
        if (tid == 0) invs[row] = inv;
    }
}

// ================== fallback path (R3-proven 128^2 dbuf GEMM) ==================
template<int AMODE, int EPI>
__global__ __launch_bounds__(256)
void gemm_k(const void* __restrict__ Ap, const unsigned short* __restrict__ Bp,
            const float* __restrict__ b0, const float* __restrict__ b1,
            const float* __restrict__ b2, const int* __restrict__ maskp,
            void* __restrict__ Cp, void* __restrict__ Cp2,
            int K, int lda, int ldb, int ldc,
            long aStride, long bStride, long cStride, long mStride, float scale)
{
    __shared__ __align__(16) unsigned short sh[2][2][128][64];
    const int tid  = threadIdx.x;
    const int z    = blockIdx.z;
    const int row0 = blockIdx.y * 128;
    const int col0 = blockIdx.x * 128;
    const int wave = tid >> 6, lane = tid & 63;
    const int lr = lane & 15, lg = lane >> 4;
    const int wm = (wave >> 1) * 64, wn = (wave & 1) * 64;
    const unsigned short* Bb = Bp + (size_t)bStride * z;
    f32x4 acc[4][4] = {};
    const int nt = K >> 6;
    auto stage = [&](int b, int k0) {
        if (AMODE == 0) {
            const unsigned short* A = (const unsigned short*)Ap + (size_t)aStride * z;
#pragma unroll
            for (int q = 0; q < 4; ++q) {
                int c = q * 256 + tid;
                int row = c >> 3, j = c & 7;
                gld16((const char*)(A + (size_t)(row0 + row) * lda + k0) + ((j ^ (row & 7)) << 4),
                      (char*)&sh[b][0][0][0] + ((q * 256 + (tid & 192)) << 4));
            }
        } else {
            const float* A = (const float*)Ap + (size_t)aStride * z;
#pragma unroll
            for (int q = 0; q < 4; ++q) {
                int c = q * 256 + tid;
                int row = c >> 3, j = c & 7;
                const float* src = A + (size_t)(row0 + row) * lda + k0 + ((j ^ (row & 7)) << 3);
                float4 v0 = *(const float4*)src;
                float4 v1 = *(const float4*)(src + 4);
                uint4 p;
                p.x = (unsigned)f2bf(v0.x) | ((unsigned)f2bf(v0.y) << 16);
                p.y = (unsigned)f2bf(v0.z) | ((unsigned)f2bf(v0.w) << 16);
                p.z = (unsigned)f2bf(v1.x) | ((unsigned)f2bf(v1.y) << 16);
                p.w = (unsigned)f2bf(v1.z) | ((unsigned)f2bf(v1.w) << 16);
                *(uint4*)((char*)&sh[b][0][0][0] + ((size_t)c << 4)) = p;
            }
        }
#pragma unroll
        for (int q = 0; q < 4; ++q) {
            int c = q * 256 + tid;
            int row = c >> 3, j = c & 7;
            gld16((const char*)(Bb + (size_t)(col0 + row) * ldb + k0) + ((j ^ (row & 7)) << 4),
                  (char*)&sh[b][1][0][0] + ((q * 256 + (tid & 192)) << 4));
        }
    };
    stage(0, 0);
    __syncthreads();
    int cur = 0;
    for (int t = 0; t < nt; ++t) {
        if (t + 1 < nt) stage(cur ^ 1, (t + 1) << 6);
        const char* baseA = (const char*)&sh[cur][0][0][0];
        const char* baseB = (const char*)&sh[cur][1][0][0];
        bf16x8 af[2][4], bfv[2][4];
#pragma unroll
        for (int s = 0; s < 2; ++s)
#pragma unroll
            for (int i = 0; i < 4; ++i) {
                int ra = wm + i * 16 + lr;
                af[s][i]  = *(const bf16x8*)(baseA + ra * 128 + ((((s << 2) | lg) ^ (ra & 7)) << 4));
                int rb = wn + i * 16 + lr;
                bfv[s][i] = *(const bf16x8*)(baseB + rb * 128 + ((((s << 2) | lg) ^ (rb & 7)) << 4));
            }
#pragma unroll
        for (int s = 0; s < 2; ++s)
#pragma unroll
            for (int mi = 0; mi < 4; ++mi)
#pragma unroll
                for (int ni = 0; ni < 4; ++ni)
                    acc[mi][ni] = __builtin_amdgcn_mfma_f32_16x16x32_bf16(af[s][mi], bfv[s][ni], acc[mi][ni], 0, 0, 0);
        if (t + 1 < nt) __syncthreads();
        cur ^= 1;
    }
    if (EPI == 6) {
        int w = col0 >> 10;
        int cb = (col0 & 1023) + wn;
        if (w < 2) {
            unsigned short* C = (unsigned short*)Cp + (size_t)w * ((size_t)B_ * S_ * DATT);
            const float* bias = w ? b1 : b0;
#pragma unroll
            for (int mi = 0; mi < 4; ++mi)
#pragma unroll
                for (int ni = 0; ni < 4; ++ni) {
                    int col = cb + ni * 16 + lr;
                    float bb = bias[col];
                    int rowb = row0 + wm + mi * 16 + lg * 4;
#pragma unroll
                    for (int v = 0; v < 4; ++v)
                        C[(size_t)(rowb + v) * DATT + col] = f2bf(acc[mi][ni][v] + bb);
                }
        } else {
            unsigned short* C = (unsigned short*)Cp2;
            int zz = row0 >> 11;
            int sb = (row0 & 2047) + wm;
#pragma unroll
            for (int mi = 0; mi < 4; ++mi)
#pragma unroll
                for (int ni = 0; ni < 4; ++ni) {
                    int col = cb + ni * 16 + lr;
                    float bb = b2[col];
                    unsigned short r[4];
#pragma unroll
                    for (int v = 0; v < 4; ++v) {
                        float xv = acc[mi][ni][v] + bb;
                        xv = 0.5f * xv * (1.0f + erff(xv * 0.70710678118654752f));
                        r[v] = f2bf(xv);
                    }
                    uint2 o;
                    o.x = (unsigned)r[0] | ((unsigned)r[1] << 16);
                    o.y = (unsigned)r[2] | ((unsigned)r[3] << 16);
                    *(uint2*)(C + ((size_t)zz * DHID + col) * S_ + sb + mi * 16 + lg * 4) = o;
                }
        }
    } else {
        float* C = (float*)Cp + (size_t)cStride * z;
        const int* mp = (EPI == 2) ? (maskp + (size_t)mStride * z) : nullptr;
#pragma unroll
        for (int mi = 0; mi < 4; ++mi)
#pragma unroll
            for (int ni = 0; ni < 4; ++ni) {
                int col = col0 + wn + ni * 16 + lr;
                int rowb = row0 + wm + mi * 16 + lg * 4;
#pragma unroll
                for (int v = 0; v < 4; ++v) {
                    float val = acc[mi][ni][v];
                    if (EPI == 2) val = val * scale + (float)mp[(size_t)(rowb + v) * ldc + col] * (-1e9f);
                    C[(size_t)(rowb + v) * ldc + col] = val;
                }
            }
    }
}

__global__ __launch_bounds__(256)
void softmax_k(float* __restrict__ attn)
{
    const int row = blockIdx.x;
    float* p = attn + (size_t)row * S_;
    const int tid = threadIdx.x;
    float4 a = ((const float4*)p)[tid * 2];
    float4 b = ((const float4*)p)[tid * 2 + 1];
    float m = fmaxf(fmaxf(fmaxf(a.x, a.y), fmaxf(a.z, a.w)),
                    fmaxf(fmaxf(b.x, b.y), fmaxf(b.z, b.w)));
#pragma unroll
    for (int o = 32; o; o >>= 1) m = fmaxf(m, __shfl_xor(m, o));
    __shared__ float redm[4];
    __shared__ float reds[4];
    if ((tid & 63) == 0) redm[tid >> 6] = m;
    __syncthreads();
    m = fmaxf(fmaxf(redm[0], redm[1]), fmaxf(redm[2], redm[3]));
    float e[8];
    e[0] = expf(a.x - m); e[1] = expf(a.y - m); e[2] = expf(a.z - m); e[3] = expf(a.w - m);
    e[4] = expf(b.x - m); e[5] = expf(b.y - m); e[6] = expf(b.z - m); e[7] = expf(b.w - m);
    float s = e[0] + e[1] + e[2] + e[3] + e[4] + e[5] + e[6] + e[7];
#pragma unroll
    for (int o = 32; o; o >>= 1) s += __shfl_xor(s, o);
    if ((tid & 63) == 0) reds[tid >> 6] = s;
    __syncthreads();
    s = reds[0] + reds[1] + reds[2] + reds[3];
    float inv = 1.0f / s;
    ((float4*)p)[tid * 2]     = make_float4(e[0] * inv, e[1] * inv, e[2] * inv, e[3] * inv);
    ((float4*)p)[tid * 2 + 1] = make_float4(e[4] * inv, e[5] * inv, e[6] * inv, e[7] * inv);
}

extern "C" void kernel_launch(void* const* d_in, const int* in_sizes, int n_in,
                              void* d_out, int out_size, void* d_ws, size_t ws_size,
                              hipStream_t stream)
{
    const float* x    = (const float*)d_in[0];
    const int*   mask = (const int*)d_in[1];
    const float* Wq   = (const float*)d_in[2];
    const float* bq   = (const float*)d_in[3];
    const float* Wk   = (const float*)d_in[4];
    const float* bk   = (const float*)d_in[5];
    const float* Wv   = (const float*)d_in[6];
    const float* bv   = (const float*)d_in[7];

    float* ctx  = (float*)d_out;                       // [B,S,DHID] fp32
    float* attn = ctx + (size_t)B_ * S_ * DHID;        // [B,S,S]    fp32

    unsigned short* Qb = (unsigned short*)ctx;                 // ctx region scratch
    unsigned short* Kb = Qb + (size_t)B_ * S_ * DATT;
    unsigned short* Xb   = (unsigned short*)attn;              // attn region scratch
    unsigned short* Wb   = Xb + (size_t)B_ * S_ * DIN;
    unsigned short* WVbT = Wb + (size_t)3 * DIN * DATT;

    const size_t eElems = (size_t)B_ * S_ * S_;
    bool fast = ws_size >= eElems * 2 + (size_t)B_ * S_ * 4 + 256;

    dim3 blk(256), blk5(512);

    xcvt_k<<<dim3(4096), blk, 0, stream>>>(x, Xb);
    wcvt_k<<<dim3(256, 3), blk, 0, stream>>>(Wq, Wk, Wv, Wb);

    if (fast) {
        unsigned short* e    = (unsigned short*)d_ws;
        float*          invs = (float*)(e + eElems);

        // fused QKV: [8192,3072] = Xb @ Wb^T (+bias); V third gets gelu + transpose
        gemm256_k<6><<<dim3(12, 32, 1), blk5, 0, stream>>>(
            Xb, Wb, bq, bk, bv, nullptr, Qb, WVbT,
            DIN, DIN, DIN, 0, 0, 0, 0, 0, 1.0f);
        // e = exp(QK^T/32), masked -> 0, bf16
        gemm256_k<4><<<dim3(8, 8, 4), blk5, 0, stream>>>(
            Qb, Kb, nullptr, nullptr, nullptr, mask, e, nullptr,
            DATT, DATT, DATT, S_,
            (long)S_ * DATT, (long)S_ * DATT, (long)S_ * S_, (long)S_ * S_, 0.03125f);
        // row sums -> invs
        rownorm_k<false><<<dim3(B_ * S_), blk, 0, stream>>>(e, nullptr, invs);
        // ctx = (e @ WV) * inv_rowsum
        gemm256_k<5><<<dim3(4, 8, 4), blk5, 0, stream>>>(
            e, WVbT, invs, nullptr, nullptr, nullptr, ctx, nullptr,
            S_, S_, S_, DHID,
            (long)S_ * S_, (long)DHID * S_, (long)S_ * DHID, 0, 1.0f);
        // attn = e * inv_rowsum (fp32) — LAST, clobbers Xb/Wb/WVbT
        rownorm_k<true><<<dim3(B_ * S_), blk, 0, stream>>>(e, attn, nullptr);
    } else {
        unsigned short* WVw = (unsigned short*)d_ws;
        gemm_k<0, 6><<<dim3(24, 64, 1), blk, 0, stream>>>(
            Xb, Wb, bq, bk, bv, nullptr, Qb, WVw,
            DIN, DIN, DIN, 0, 0, 0, 0, 0, 1.0f);
        gemm_k<0, 2><<<dim3(16, 16, 4), blk, 0, stream>>>(
            Qb, Kb, nullptr, nullptr, nullptr, mask, attn, nullptr,
            DATT, DATT, DATT, S_,
            (long)S_ * DATT, (long)S_ * DATT, (long)S_ * S_, (long)S_ * S_, 0.03125f);
        softmax_k<<<dim3(B_ * S_), blk, 0, stream>>>(attn);
        gemm_k<1, 3><<<dim3(8, 16, 4), blk, 0, stream>>>(
            attn, WVw, nullptr, nullptr, nullptr, nullptr, ctx, nullptr,
            S_, S_, S_, DHID,
            (long)S_ * S_, (long)DHID * S_, (long)S_ * DHID, 0, 1.0f);
    }
}

// Round 5
// 233.176 us; speedup vs baseline: 1.0423x; 1.0423x over previous
//
#include <hip/hip_runtime.h>
#include <hip/hip_bf16.h>
#include <math.h>

#define B_   4
#define S_   2048
#define DIN  1024
#define DATT 1024
#define DHID 1024

typedef short bf16x8 __attribute__((ext_vector_type(8)));
typedef float f32x4  __attribute__((ext_vector_type(4)));

__device__ inline unsigned short f2bf(float f) {
    unsigned u = __float_as_uint(f);
    u += 0x7fffu + ((u >> 16) & 1u);
    return (unsigned short)(u >> 16);
}
__device__ inline float bf2f(unsigned u16) {
    return __uint_as_float(u16 << 16);
}
__device__ inline void gld16(const void* g, void* l) {
    __builtin_amdgcn_global_load_lds(
        (const __attribute__((address_space(1))) unsigned int*)g,
        (__attribute__((address_space(3))) unsigned int*)l, 16, 0, 0);
}

// ---------------- prep: X fp32 -> bf16 ----------------
__global__ __launch_bounds__(256)
void xcvt_k(const float* __restrict__ x, unsigned short* __restrict__ xb)
{
    int i = blockIdx.x * 256 + threadIdx.x;
    const float4* p = (const float4*)x + (size_t)i * 2;
    float4 v0 = p[0], v1 = p[1];
    uint4 o;
    o.x = (unsigned)f2bf(v0.x) | ((unsigned)f2bf(v0.y) << 16);
    o.y = (unsigned)f2bf(v0.z) | ((unsigned)f2bf(v0.w) << 16);
    o.z = (unsigned)f2bf(v1.x) | ((unsigned)f2bf(v1.y) << 16);
    o.w = (unsigned)f2bf(v1.z) | ((unsigned)f2bf(v1.w) << 16);
    ((uint4*)xb)[i] = o;
}

// ---------------- prep: W [K][N] fp32 -> Wt [N][K] bf16 ----------------
__global__ __launch_bounds__(256)
void wcvt_k(const float* __restrict__ Wq, const float* __restrict__ Wk,
            const float* __restrict__ Wv, unsigned short* __restrict__ Wt)
{
    int w = blockIdx.y;
    const float* W = (w == 0) ? Wq : ((w == 1) ? Wk : Wv);
    unsigned short* D = Wt + (size_t)w * DIN * DATT;
    int t = blockIdx.x * 256 + threadIdx.x;
    int n  = t >> 6;
    int kc = (t & 63) * 16;
    unsigned short r[16];
#pragma unroll
    for (int i = 0; i < 16; ++i) r[i] = f2bf(W[(size_t)(kc + i) * DATT + n]);
    uint4 o0, o1;
    o0.x = (unsigned)r[0] | ((unsigned)r[1] << 16);  o0.y = (unsigned)r[2] | ((unsigned)r[3] << 16);
    o0.z = (unsigned)r[4] | ((unsigned)r[5] << 16);  o0.w = (unsigned)r[6] | ((unsigned)r[7] << 16);
    o1.x = (unsigned)r[8] | ((unsigned)r[9] << 16);  o1.y = (unsigned)r[10] | ((unsigned)r[11] << 16);
    o1.z = (unsigned)r[12] | ((unsigned)r[13] << 16); o1.w = (unsigned)r[14] | ((unsigned)r[15] << 16);
    *(uint4*)(D + (size_t)n * DIN + kc)     = o0;
    *(uint4*)(D + (size_t)n * DIN + kc + 8) = o1;
}

// ---------------- prep: pack mask int32 -> bits (bit b of word w = mask[32w+b]!=0) ----
__global__ __launch_bounds__(256)
void mpack_k(const int* __restrict__ m, unsigned* __restrict__ mb)
{
    int w = blockIdx.x * 256 + threadIdx.x;
    const uint4* p = (const uint4*)(m + (size_t)w * 32);
    unsigned bits = 0;
#pragma unroll
    for (int g = 0; g < 8; ++g) {
        uint4 v = p[g];
        bits |= (v.x ? 1u : 0u) << (g * 4 + 0);
        bits |= (v.y ? 1u : 0u) << (g * 4 + 1);
        bits |= (v.z ? 1u : 0u) << (g * 4 + 2);
        bits |= (v.w ? 1u : 0u) << (g * 4 + 3);
    }
    mb[w] = bits;
}

// ======== config A: 256x256, 8 waves 2x4, BK=64, 4 phases, bv-reuse (e-GEMM only) ====
// EPI: e = exp(val*scale), masked(bit)->0, bf16 out
__global__ __launch_bounds__(512, 2)
void gemmA_k(const unsigned short* __restrict__ Ap, const unsigned short* __restrict__ Bp,
             const unsigned* __restrict__ mbits, unsigned short* __restrict__ Cp,
             int K, int lda, int ldb, int ldc,
             long aStride, long bStride, long cStride, float scale)
{
    __shared__ __align__(16) char ldsb[131072];

    const int tid  = threadIdx.x;
    const int z    = blockIdx.z;
    const int row0 = blockIdx.y * 256;
    const int col0 = blockIdx.x * 256;
    const int wid  = tid >> 6, lane = tid & 63;
    const int lr = lane & 15, lg = lane >> 4;
    const int wm = wid >> 2, wn = wid & 3;
    const int tw = (tid & 448) * 16;

    const unsigned short* Ab = Ap + (size_t)aStride * z;
    const unsigned short* Bb = Bp + (size_t)bStride * z;

    const int swzA = lr & 7;
    const int swzB = lg ^ ((lr >> 1) & 3);

    f32x4 acc[8][4] = {};
    const int nt = K >> 6;

#define STAGE_A(buf, k0n, r) {                                                  \
    int gr = (((r) & 1) << 7) + (((r) >> 1) << 6) + (tid >> 3);                 \
    int jj = (tid & 7) ^ (gr & 7);                                              \
    gld16(Ab + (size_t)(row0 + gr) * lda + (k0n) + jj * 8,                      \
          ldsb + (size_t)(buf) * 65536 + (r) * 8192 + tw); }

#define STAGE_B(buf, k0n, r) {                                                  \
    int rw = (((r) & 1) << 7) + (tid >> 2);                                     \
    int jj = (tid & 3) ^ ((rw >> 1) & 3);                                       \
    gld16(Bb + (size_t)(col0 + rw) * ldb + (k0n) + ((r) >> 1) * 32 + jj * 8,    \
          ldsb + (size_t)(buf) * 65536 + 32768 + ((r) >> 1) * 16384             \
               + (((r) & 1) << 13) + tw); }

#define PHASE_A(mh, kk, BV, LOADB, DOSTAGE) {                                   \
    const char* lb = ldsb + (size_t)cb * 65536;                                 \
    bf16x8 av[4];                                                               \
    _Pragma("unroll")                                                           \
    for (int m = 0; m < 4; ++m) {                                               \
        int Rl = (mh) * 128 + wm * 64 + m * 16 + lr;                            \
        av[m] = *(const bf16x8*)(lb + Rl * 128 + ((((kk) * 4 + lg) ^ swzA) << 4)); \
    }                                                                           \
    if (LOADB) {                                                                \
        _Pragma("unroll")                                                       \
        for (int n = 0; n < 4; ++n) {                                           \
            int Rb = wn * 64 + n * 16 + lr;                                     \
            BV[n] = *(const bf16x8*)(lb + 32768 + (kk) * 16384 + Rb * 64 + (swzB << 4)); \
        }                                                                       \
    }                                                                           \
    DOSTAGE;                                                                    \
    asm volatile("s_waitcnt lgkmcnt(0)" ::: "memory");                          \
    __builtin_amdgcn_sched_barrier(0);                                          \
    __builtin_amdgcn_s_setprio(1);                                              \
    _Pragma("unroll")                                                           \
    for (int m = 0; m < 4; ++m)                                                 \
        _Pragma("unroll")                                                       \
        for (int n = 0; n < 4; ++n)                                             \
            acc[(mh) * 4 + m][n] = __builtin_amdgcn_mfma_f32_16x16x32_bf16(     \
                av[m], BV[n], acc[(mh) * 4 + m][n], 0, 0, 0);                   \
    __builtin_amdgcn_s_setprio(0); }

    STAGE_A(0, 0, 0); STAGE_B(0, 0, 0);
    STAGE_A(0, 0, 1); STAGE_B(0, 0, 1);
    STAGE_A(0, 0, 2); STAGE_A(0, 0, 3);
    STAGE_B(0, 0, 2); STAGE_B(0, 0, 3);

    int cb = 0;
    for (int t = 0; t < nt; ++t) {
        const bool pf = (t + 1) < nt;
        const int k0n = (t + 1) << 6;
        const int nb = cb ^ 1;
        bf16x8 bv0[4], bv1[4];
        asm volatile("s_waitcnt vmcnt(4)\ns_barrier" ::: "memory");
        PHASE_A(0, 0, bv0, true,  if (pf) { STAGE_A(nb, k0n, 0); STAGE_B(nb, k0n, 0); })
        if (pf) asm volatile("s_waitcnt vmcnt(4)\ns_barrier" ::: "memory");
        else    asm volatile("s_waitcnt vmcnt(2)\ns_barrier" ::: "memory");
        PHASE_A(1, 0, bv0, false, if (pf) { STAGE_A(nb, k0n, 1); STAGE_B(nb, k0n, 1); })
        if (pf) asm volatile("s_waitcnt vmcnt(4)\ns_barrier" ::: "memory");
        else    asm volatile("s_waitcnt vmcnt(0)\ns_barrier" ::: "memory");
        PHASE_A(0, 1, bv1, true,  if (pf) { STAGE_A(nb, k0n, 2); STAGE_A(nb, k0n, 3); })
        PHASE_A(1, 1, bv1, false, if (pf) { STAGE_B(nb, k0n, 2); STAGE_B(nb, k0n, 3); })
        cb = nb;
    }
#undef PHASE_A
#undef STAGE_A
#undef STAGE_B

    // epilogue: e = bit ? 0 : exp(acc*scale), bf16
    unsigned short* C = Cp + (size_t)cStride * z;
    const unsigned* mb = mbits + (size_t)z * (S_ * S_ / 32);
    const int wbase = (col0 + wn * 64) >> 5;
#pragma unroll
    for (int mi = 0; mi < 8; ++mi) {
        int rowb = row0 + wm * 128 + mi * 16 + lg * 4;
#pragma unroll
        for (int v = 0; v < 4; ++v) {
            int row = rowb + v;
            unsigned w0 = mb[(size_t)row * (S_ / 32) + wbase];
            unsigned w1 = mb[(size_t)row * (S_ / 32) + wbase + 1];
#pragma unroll
            for (int ni = 0; ni < 4; ++ni) {
                int col = col0 + wn * 64 + ni * 16 + lr;
                unsigned wsel = (ni & 2) ? w1 : w0;
                float ev = ((wsel >> ((ni & 1) * 16 + lr)) & 1)
                         ? 0.0f : __expf(acc[mi][ni][v] * scale);
                C[(size_t)row * ldc + col] = f2bf(ev);
            }
        }
    }
}

// ======== config B: 256x128, 8 waves 4x2, BK=64, 4 frag-granular phases ========
// A LDS (32KB): byte = m*8192 + region*2048 + fragrow*128 + (slot^(fragrow&7))*16
//   round A_m = frag m rows of all 4 regions (one gld/thread).
// B LDS (16KB at 32768): kk-major [2][128][32]: byte = kk*8192 + Rb*64 + (slot^((Rb>>1)&3))*16
// Rounds/tile: A0,A1,B0,A2,A3,B1 ; issue ph0:{A0,A1} ph1:{B0} ph2:{A2,A3} ph3:{B1}
// vmcnt: entry ph0:3, ph1: pf?3:1, ph2: pf?3:0, ph3: none.
// EPI: 6 = fused QKV (Q/K bf16+bias; V gelu+bias transposed to Cp2); 5 = fp32 out * invs[row]
template<int EPI>
__global__ __launch_bounds__(512, 2)
void gemmB_k(const unsigned short* __restrict__ Ap, const unsigned short* __restrict__ Bp,
             const float* __restrict__ b0, const float* __restrict__ b1,
             const float* __restrict__ b2,
             void* __restrict__ Cp, void* __restrict__ Cp2,
             int K, int lda, int ldb, int ldc,
             long aStride, long bStride, long cStride, float scale)
{
    __shared__ __align__(16) char ldsb[98304];   // 2 x 48KB

    const int tid  = threadIdx.x;
    const int z    = blockIdx.z;
    const int row0 = blockIdx.y * 256;
    const int col0 = blockIdx.x * 128;
    const int wid  = tid >> 6, lane = tid & 63;
    const int lr = lane & 15, lg = lane >> 4;
    const int wm = wid >> 1, wn = wid & 1;
    const int tw = (tid & 448) * 16;

    const unsigned short* Ab = Ap + (size_t)aStride * z;
    const unsigned short* Bb = Bp + (size_t)bStride * z;

    const int swzA = lr & 7;
    const int swzB = lg ^ ((lr >> 1) & 3);

    f32x4 acc[4][4] = {};
    const int nt = K >> 6;

#define STAGE_AB(buf, k0n, m) {                                                 \
    int fr = (tid >> 3) & 15, j = tid & 7;                                      \
    int gr = ((tid >> 7) << 6) + (m) * 16 + fr;                                 \
    gld16(Ab + (size_t)(row0 + gr) * lda + (k0n) + ((j ^ (fr & 7)) << 3),       \
          ldsb + (size_t)(buf) * 49152 + (m) * 8192 + tw); }

#define STAGE_BB(buf, k0n, kk) {                                                \
    int rw = tid >> 2;                                                          \
    int jj = (tid & 3) ^ ((rw >> 1) & 3);                                       \
    gld16(Bb + (size_t)(col0 + rw) * ldb + (k0n) + (kk) * 32 + (jj << 3),       \
          ldsb + (size_t)(buf) * 49152 + 32768 + (kk) * 8192 + tw); }

#define PHASE_B(rh, kk, BV, LOADB, DOSTAGE) {                                   \
    const char* lb = ldsb + (size_t)cb * 49152;                                 \
    bf16x8 av[2];                                                               \
    _Pragma("unroll")                                                           \
    for (int mm = 0; mm < 2; ++mm) {                                            \
        int m = (rh) * 2 + mm;                                                  \
        av[mm] = *(const bf16x8*)(lb + m * 8192 + wm * 2048 + lr * 128          \
                                  + ((((kk) * 4 + lg) ^ swzA) << 4));           \
    }                                                                           \
    if (LOADB) {                                                                \
        _Pragma("unroll")                                                       \
        for (int n = 0; n < 4; ++n) {                                           \
            int Rb = wn * 64 + n * 16 + lr;                                     \
            BV[n] = *(const bf16x8*)(lb + 32768 + (kk) * 8192 + Rb * 64 + (swzB << 4)); \
        }                                                                       \
    }                                                                           \
    DOSTAGE;                                                                    \
    asm volatile("s_waitcnt lgkmcnt(0)" ::: "memory");                          \
    __builtin_amdgcn_sched_barrier(0);                                          \
    __builtin_amdgcn_s_setprio(1);                                              \
    _Pragma("unroll")                                                           \
    for (int mm = 0; mm < 2; ++mm)                                              \
        _Pragma("unroll")                                                       \
        for (int n = 0; n < 4; ++n)                                             \
            acc[(rh) * 2 + mm][n] = __builtin_amdgcn_mfma_f32_16x16x32_bf16(    \
                av[mm], BV[n], acc[(rh) * 2 + mm][n], 0, 0, 0);                 \
    __builtin_amdgcn_s_setprio(0); }

    // prologue in deadline order
    STAGE_AB(0, 0, 0); STAGE_AB(0, 0, 1); STAGE_BB(0, 0, 0);
    STAGE_AB(0, 0, 2); STAGE_AB(0, 0, 3); STAGE_BB(0, 0, 1);

    int cb = 0;
    for (int t = 0; t < nt; ++t) {
        const bool pf = (t + 1) < nt;
        const int k0n = (t + 1) << 6;
        const int nb = cb ^ 1;
        bf16x8 bv0[4], bv1[4];
        asm volatile("s_waitcnt vmcnt(3)\ns_barrier" ::: "memory");
        PHASE_B(0, 0, bv0, true,  if (pf) { STAGE_AB(nb, k0n, 0); STAGE_AB(nb, k0n, 1); })
        if (pf) asm volatile("s_waitcnt vmcnt(3)\ns_barrier" ::: "memory");
        else    asm volatile("s_waitcnt vmcnt(1)\ns_barrier" ::: "memory");
        PHASE_B(1, 0, bv0, false, if (pf) { STAGE_BB(nb, k0n, 0); })
        if (pf) asm volatile("s_waitcnt vmcnt(3)\ns_barrier" ::: "memory");
        else    asm volatile("s_waitcnt vmcnt(0)\ns_barrier" ::: "memory");
        PHASE_B(0, 1, bv1, true,  if (pf) { STAGE_AB(nb, k0n, 2); STAGE_AB(nb, k0n, 3); })
        PHASE_B(1, 1, bv1, false, if (pf) { STAGE_BB(nb, k0n, 1); })
        cb = nb;
    }
#undef PHASE_B
#undef STAGE_AB
#undef STAGE_BB

    // epilogue: row = row0 + wm*64 + mi*16 + lg*4 + v ; col = col0 + wn*64 + ni*16 + lr
    if (EPI == 6) {
        int w = col0 >> 10;
        int cb0 = (col0 & 1023) + wn * 64;
        if (w < 2) {
            unsigned short* C = (unsigned short*)Cp + (size_t)w * ((size_t)B_ * S_ * DATT);
            const float* bias = w ? b1 : b0;
#pragma unroll
            for (int ni = 0; ni < 4; ++ni) {
                int col = cb0 + ni * 16 + lr;
                float bb = bias[col];
#pragma unroll
                for (int mi = 0; mi < 4; ++mi) {
                    int rowb = row0 + wm * 64 + mi * 16 + lg * 4;
#pragma unroll
                    for (int v = 0; v < 4; ++v)
                        C[(size_t)(rowb + v) * DATT + col] = f2bf(acc[mi][ni][v] + bb);
                }
            }
        } else {
            unsigned short* C = (unsigned short*)Cp2;
            int zz = row0 >> 11;
            int sb = (row0 & 2047) + wm * 64;
#pragma unroll
            for (int ni = 0; ni < 4; ++ni) {
                int col = cb0 + ni * 16 + lr;
                float bb = b2[col];
#pragma unroll
                for (int mi = 0; mi < 4; ++mi) {
                    unsigned short r[4];
#pragma unroll
                    for (int v = 0; v < 4; ++v) {
                        float xv = acc[mi][ni][v] + bb;
                        xv = 0.5f * xv * (1.0f + erff(xv * 0.70710678118654752f));
                        r[v] = f2bf(xv);
                    }
                    uint2 o;
                    o.x = (unsigned)r[0] | ((unsigned)r[1] << 16);
                    o.y = (unsigned)r[2] | ((unsigned)r[3] << 16);
                    *(uint2*)(C + ((size_t)zz * DHID + col) * S_ + sb + mi * 16 + lg * 4) = o;
                }
            }
        }
    } else {  // EPI == 5
        float* C = (float*)Cp + (size_t)cStride * z;
        const float* invs = b0 + (size_t)z * S_;
#pragma unroll
        for (int mi = 0; mi < 4; ++mi) {
            int rowb = row0 + wm * 64 + mi * 16 + lg * 4;
#pragma unroll
            for (int ni = 0; ni < 4; ++ni) {
                int col = col0 + wn * 64 + ni * 16 + lr;
#pragma unroll
                for (int v = 0; v < 4; ++v)
                    C[(size_t)(rowb + v) * ldc + col] = acc[mi][ni][v] * invs[rowb + v];
            }
        }
    }
}

// ---------------- rowsum / normalize over e (bf16 rows of 2048) ----------------
template<bool WRITEATTN>
__global__ __launch_bounds__(256)
void rownorm_k(const unsigned short* __restrict__ e, float* __restrict__ attn,
               float* __restrict__ invs)
{
    const int row = blockIdx.x;
    const int tid = threadIdx.x;
    uint4 u = ((const uint4*)(e + (size_t)row * S_))[tid];
    float f[8];
    f[0] = bf2f(u.x & 0xffffu); f[1] = bf2f(u.x >> 16);
    f[2] = bf2f(u.y & 0xffffu); f[3] = bf2f(u.y >> 16);
    f[4] = bf2f(u.z & 0xffffu); f[5] = bf2f(u.z >> 16);
    f[6] = bf2f(u.w & 0xffffu); f[7] = bf2f(u.w >> 16);
    float s = ((f[0] + f[1]) + (f[2] + f[3])) + ((f[4] + f[5]) + (f[6] + f[7]));
#pragma unroll
    for (int o = 32; o; o >>= 1) s += __shfl_xor(s, o);
    __shared__ float red[4];
    if ((tid & 63) == 0) red[tid >> 6] = s;
    __syncthreads();
    s = (red[0] + red[1]) + (red[2] + red[3]);
    float inv = 1.0f / s;
    if (WRITEATTN) {
        float* p = attn + (size_t)row * S_;
        ((float4*)p)[tid * 2]     = make_float4(f[0] * inv, f[1] * inv, f[2] * inv, f[3] * inv);
        ((float4*)p)[tid * 2 + 1] = make_float4(f[4] * inv, f[5] * inv, f[6] * inv, f[7] * inv);
    } else {
        if (tid == 0) invs[row] = inv;
    }
}

// ================== fallback path (R3-proven 128^2 dbuf GEMM) ==================
template<int AMODE, int EPI>
__global__ __launch_bounds__(256)
void gemm_k(const void* __restrict__ Ap, const unsigned short* __restrict__ Bp,
            const float* __restrict__ b0, const float* __restrict__ b1,
            const float* __restrict__ b2, const int* __restrict__ maskp,
            void* __restrict__ Cp, void* __restrict__ Cp2,
            int K, int lda, int ldb, int ldc,
            long aStride, long bStride, long cStride, long mStride, float scale)
{
    __shared__ __align__(16) unsigned short sh[2][2][128][64];
    const int tid  = threadIdx.x;
    const int z    = blockIdx.z;
    const int row0 = blockIdx.y * 128;
    const int col0 = blockIdx.x * 128;
    const int wave = tid >> 6, lane = tid & 63;
    const int lr = lane & 15, lg = lane >> 4;
    const int wm = (wave >> 1) * 64, wn = (wave & 1) * 64;
    const unsigned short* Bb = Bp + (size_t)bStride * z;
    f32x4 acc[4][4] = {};
    const int nt = K >> 6;
    auto stage = [&](int b, int k0) {
        if (AMODE == 0) {
            const unsigned short* A = (const unsigned short*)Ap + (size_t)aStride * z;
#pragma unroll
            for (int q = 0; q < 4; ++q) {
                int c = q * 256 + tid;
                int row = c >> 3, j = c & 7;
                gld16((const char*)(A + (size_t)(row0 + row) * lda + k0) + ((j ^ (row & 7)) << 4),
                      (char*)&sh[b][0][0][0] + ((q * 256 + (tid & 192)) << 4));
            }
        } else {
            const float* A = (const float*)Ap + (size_t)aStride * z;
#pragma unroll
            for (int q = 0; q < 4; ++q) {
                int c = q * 256 + tid;
                int row = c >> 3, j = c & 7;
                const float* src = A + (size_t)(row0 + row) * lda + k0 + ((j ^ (row & 7)) << 3);
                float4 v0 = *(const float4*)src;
                float4 v1 = *(const float4*)(src + 4);
                uint4 p;
                p.x = (unsigned)f2bf(v0.x) | ((unsigned)f2bf(v0.y) << 16);
                p.y = (unsigned)f2bf(v0.z) | ((unsigned)f2bf(v0.w) << 16);
                p.z = (unsigned)f2bf(v1.x) | ((unsigned)f2bf(v1.y) << 16);
                p.w = (unsigned)f2bf(v1.z) | ((unsigned)f2bf(v1.w) << 16);
                *(uint4*)((char*)&sh[b][0][0][0] + ((size_t)c << 4)) = p;
            }
        }
#pragma unroll
        for (int q = 0; q < 4; ++q) {
            int c = q * 256 + tid;
            int row = c >> 3, j = c & 7;
            gld16((const char*)(Bb + (size_t)(col0 + row) * ldb + k0) + ((j ^ (row & 7)) << 4),
                  (char*)&sh[b][1][0][0] + ((q * 256 + (tid & 192)) << 4));
        }
    };
    stage(0, 0);
    __syncthreads();
    int cur = 0;
    for (int t = 0; t < nt; ++t) {
        if (t + 1 < nt) stage(cur ^ 1, (t + 1) << 6);
        const char* baseA = (const char*)&sh[cur][0][0][0];
        const char* baseB = (const char*)&sh[cur][1][0][0];
        bf16x8 af[2][4], bfv[2][4];
#pragma unroll
        for (int s = 0; s < 2; ++s)
#pragma unroll
            for (int i = 0; i < 4; ++i) {
                int ra = wm + i * 16 + lr;
                af[s][i]  = *(const bf16x8*)(baseA + ra * 128 + ((((s << 2) | lg) ^ (ra & 7)) << 4));
                int rb = wn + i * 16 + lr;
                bfv[s][i] = *(const bf16x8*)(baseB + rb * 128 + ((((s << 2) | lg) ^ (rb & 7)) << 4));
            }
#pragma unroll
        for (int s = 0; s < 2; ++s)
#pragma unroll
            for (int mi = 0; mi < 4; ++mi)
#pragma unroll
                for (int ni = 0; ni < 4; ++ni)
                    acc[mi][ni] = __builtin_amdgcn_mfma_f32_16x16x32_bf16(af[s][mi], bfv[s][ni], acc[mi][ni], 0, 0, 0);
        if (t + 1 < nt) __syncthreads();
        cur ^= 1;
    }
    if (EPI == 6) {
        int w = col0 >> 10;
        int cb = (col0 & 1023) + wn;
        if (w < 2) {
            unsigned short* C = (unsigned short*)Cp + (size_t)w * ((size_t)B_ * S_ * DATT);
            const float* bias = w ? b1 : b0;
#pragma unroll
            for (int mi = 0; mi < 4; ++mi)
#pragma unroll
                for (int ni = 0; ni < 4; ++ni) {
                    int col = cb + ni * 16 + lr;
                    float bb = bias[col];
                    int rowb = row0 + wm + mi * 16 + lg * 4;
#pragma unroll
                    for (int v = 0; v < 4; ++v)
                        C[(size_t)(rowb + v) * DATT + col] = f2bf(acc[mi][ni][v] + bb);
                }
        } else {
            unsigned short* C = (unsigned short*)Cp2;
            int zz = row0 >> 11;
            int sb = (row0 & 2047) + wm;
#pragma unroll
            for (int mi = 0; mi < 4; ++mi)
#pragma unroll
                for (int ni = 0; ni < 4; ++ni) {
                    int col = cb + ni * 16 + lr;
                    float bb = b2[col];
                    unsigned short r[4];
#pragma unroll
                    for (int v = 0; v < 4; ++v) {
                        float xv = acc[mi][ni][v] + bb;
                        xv = 0.5f * xv * (1.0f + erff(xv * 0.70710678118654752f));
                        r[v] = f2bf(xv);
                    }
                    uint2 o;
                    o.x = (unsigned)r[0] | ((unsigned)r[1] << 16);
                    o.y = (unsigned)r[2] | ((unsigned)r[3] << 16);
                    *(uint2*)(C + ((size_t)zz * DHID + col) * S_ + sb + mi * 16 + lg * 4) = o;
                }
        }
    } else {
        float* C = (float*)Cp + (size_t)cStride * z;
        const int* mp = (EPI == 2) ? (maskp + (size_t)mStride * z) : nullptr;
#pragma unroll
        for (int mi = 0; mi < 4; ++mi)
#pragma unroll
            for (int ni = 0; ni < 4; ++ni) {
                int col = col0 + wn + ni * 16 + lr;
                int rowb = row0 + wm + mi * 16 + lg * 4;
#pragma unroll
                for (int v = 0; v < 4; ++v) {
                    float val = acc[mi][ni][v];
                    if (EPI == 2) val = val * scale + (float)mp[(size_t)(rowb + v) * ldc + col] * (-1e9f);
                    C[(size_t)(rowb + v) * ldc + col] = val;
                }
            }
    }
}

__global__ __launch_bounds__(256)
void softmax_k(float* __restrict__ attn)
{
    const int row = blockIdx.x;
    float* p = attn + (size_t)row * S_;
    const int tid = threadIdx.x;
    float4 a = ((const float4*)p)[tid * 2];
    float4 b = ((const float4*)p)[tid * 2 + 1];
    float m = fmaxf(fmaxf(fmaxf(a.x, a.y), fmaxf(a.z, a.w)),
                    fmaxf(fmaxf(b.x, b.y), fmaxf(b.z, b.w)));
#pragma unroll
    for (int o = 32; o; o >>= 1) m = fmaxf(m, __shfl_xor(m, o));
    __shared__ float redm[4];
    __shared__ float reds[4];
    if ((tid & 63) == 0) redm[tid >> 6] = m;
    __syncthreads();
    m = fmaxf(fmaxf(redm[0], redm[1]), fmaxf(redm[2], redm[3]));
    float e[8];
    e[0] = expf(a.x - m); e[1] = expf(a.y - m); e[2] = expf(a.z - m); e[3] = expf(a.w - m);
    e[4] = expf(b.x - m); e[5] = expf(b.y - m); e[6] = expf(b.z - m); e[7] = expf(b.w - m);
    float s = e[0] + e[1] + e[2] + e[3] + e[4] + e[5] + e[6] + e[7];
#pragma unroll
    for (int o = 32; o; o >>= 1) s += __shfl_xor(s, o);
    if ((tid & 63) == 0) reds[tid >> 6] = s;
    __syncthreads();
    s = reds[0] + reds[1] + reds[2] + reds[3];
    float inv = 1.0f / s;
    ((float4*)p)[tid * 2]     = make_float4(e[0] * inv, e[1] * inv, e[2] * inv, e[3] * inv);
    ((float4*)p)[tid * 2 + 1] = make_float4(e[4] * inv, e[5] * inv, e[6] * inv, e[7] * inv);
}

extern "C" void kernel_launch(void* const* d_in, const int* in_sizes, int n_in,
                              void* d_out, int out_size, void* d_ws, size_t ws_size,
                              hipStream_t stream)
{
    const float* x    = (const float*)d_in[0];
    const int*   mask = (const int*)d_in[1];
    const float* Wq   = (const float*)d_in[2];
    const float* bq   = (const float*)d_in[3];
    const float* Wk   = (const float*)d_in[4];
    const float* bk   = (const float*)d_in[5];
    const float* Wv   = (const float*)d_in[6];
    const float* bv   = (const float*)d_in[7];

    float* ctx  = (float*)d_out;                       // [B,S,DHID] fp32
    float* attn = ctx + (size_t)B_ * S_ * DHID;        // [B,S,S]    fp32

    unsigned short* Qb = (unsigned short*)ctx;                 // ctx region scratch
    unsigned short* Kb = Qb + (size_t)B_ * S_ * DATT;
    unsigned short* Xb   = (unsigned short*)attn;              // attn region scratch
    unsigned short* Wb   = Xb + (size_t)B_ * S_ * DIN;
    unsigned short* WVbT = Wb + (size_t)3 * DIN * DATT;

    const size_t eElems = (size_t)B_ * S_ * S_;
    const size_t mWords = (size_t)B_ * S_ * S_ / 32;
    bool fast = ws_size >= eElems * 2 + (size_t)B_ * S_ * 4 + mWords * 4 + 256;

    dim3 blk(256), blk5(512);

    xcvt_k<<<dim3(4096), blk, 0, stream>>>(x, Xb);
    wcvt_k<<<dim3(256, 3), blk, 0, stream>>>(Wq, Wk, Wv, Wb);

    if (fast) {
        unsigned short* e    = (unsigned short*)d_ws;          // 33.55 MB
        float*          invs = (float*)(e + eElems);           // 32 KB
        unsigned*       mb   = (unsigned*)(invs + (size_t)B_ * S_);  // 2 MB

        mpack_k<<<dim3(mWords / 256), blk, 0, stream>>>(mask, mb);
        // fused QKV (config B, 768 blocks): [8192,3072] = Xb @ Wb^T (+bias); V gets gelu+T
        gemmB_k<6><<<dim3(24, 32, 1), blk5, 0, stream>>>(
            Xb, Wb, bq, bk, bv, Qb, WVbT,
            DIN, DIN, DIN, 0, 0, 0, 0, 1.0f);
        // e = exp(QK^T/32), masked(bit) -> 0, bf16 (config A, 256 blocks)
        gemmA_k<<<dim3(8, 8, 4), blk5, 0, stream>>>(
            Qb, Kb, mb, e,
            DATT, DATT, DATT, S_,
            (long)S_ * DATT, (long)S_ * DATT, (long)S_ * S_, 0.03125f);
        // row sums -> invs
        rownorm_k<false><<<dim3(B_ * S_), blk, 0, stream>>>(e, nullptr, invs);
        // ctx = (e @ WV) * inv_rowsum (config B, 256 blocks)
        gemmB_k<5><<<dim3(8, 8, 4), blk5, 0, stream>>>(
            e, WVbT, invs, nullptr, nullptr, ctx, nullptr,
            S_, S_, S_, DHID,
            (long)S_ * S_, (long)DHID * S_, (long)S_ * DHID, 1.0f);
        // attn = e * inv_rowsum (fp32) — LAST, clobbers Xb/Wb/WVbT
        rownorm_k<true><<<dim3(B_ * S_), blk, 0, stream>>>(e, attn, nullptr);
    } else {
        unsigned short* WVw = (unsigned short*)d_ws;
        gemm_k<0, 6><<<dim3(24, 64, 1), blk, 0, stream>>>(
            Xb, Wb, bq, bk, bv, nullptr, Qb, WVw,
            DIN, DIN, DIN, 0, 0, 0, 0, 0, 1.0f);
        gemm_k<0, 2><<<dim3(16, 16, 4), blk, 0, stream>>>(
            Qb, Kb, nullptr, nullptr, nullptr, mask, attn, nullptr,
            DATT, DATT, DATT, S_,
            (long)S_ * DATT, (long)S_ * DATT, (long)S_ * S_, (long)S_ * S_, 0.03125f);
        softmax_k<<<dim3(B_ * S_), blk, 0, stream>>>(attn);
        gemm_k<1, 3><<<dim3(8, 16, 4), blk, 0, stream>>>(
            attn, WVw, nullptr, nullptr, nullptr, nullptr, ctx, nullptr,
            S_, S_, S_, DHID,
            (long)S_ * S_, (long)DHID * S_, (long)S_ * DHID, 0, 1.0f);
    }
}